// Round 5
// baseline (243.467 us; speedup 1.0000x reference)
//
#include <hip/hip_runtime.h>
#include <hip/hip_bf16.h>

// Problem constants (B=4, S=4096, A=2, H=8, DH=128, DM=2048)
#define T_TOK 16384
#define NH 8
#define DHD 128
#define DMD 2048
#define MAXTILES 192   // worst case: 64 buckets + 16384/128

typedef __attribute__((ext_vector_type(8))) short bf16x8;
typedef __attribute__((ext_vector_type(4))) float f32x4;

__device__ inline short f2b(float x) {
    __hip_bfloat16 h = __float2bfloat16(x);
    return *reinterpret_cast<short*>(&h);
}

// ---------------- ws layout (bytes) ----------------
// 0      : offs[64]
// 256    : cursor[64]   (zeroed by k_scan each call)
// 512    : ntiles
// 1024   : tiles[192][4] int
// 8192   : keys[16384]  (64 KB)
// 73728  : perm[16384]  (64 KB)
// 262144 : Wt bf16 [8][2048][128]  (4 MB)

// fused: blocks [0,64) compute keys; blocks [64,320) transpose W -> Wt bf16
__global__ __launch_bounds__(256) void k_keys_wt(
    const int* __restrict__ idx, const float* __restrict__ W,
    int* __restrict__ keys, short* __restrict__ Wt) {
    if (blockIdx.x < 64) {
        int t = blockIdx.x * 256 + threadIdx.x;
        keys[t] = idx[2 * t] * NH + idx[2 * t + 1];
    } else {
        __shared__ float Ws[DHD][65];
        int bx = blockIdx.x - 64;
        int h = bx >> 5, m0 = (bx & 31) * 64;
        int tid = threadIdx.x;
        for (int i = tid; i < DHD * 64; i += 256) {
            int d = i >> 6, m = i & 63;
            Ws[d][m] = W[((size_t)h * DHD + d) * DMD + m0 + m];
        }
        __syncthreads();
        for (int i = tid; i < 64 * 16; i += 256) {
            int m = i >> 4, d0 = (i & 15) * 8;
            bf16x8 o;
#pragma unroll
            for (int j = 0; j < 8; ++j) o[j] = f2b(Ws[d0 + j][m]);
            *(bf16x8*)(Wt + ((size_t)h * DMD + m0 + m) * DHD + d0) = o;
        }
    }
}

// single block: hist (LDS atomics) -> exclusive scan -> offs/cursor/tiles
__global__ __launch_bounds__(1024) void k_scan(
    const int* __restrict__ keys, int* __restrict__ offs, int* __restrict__ cursor,
    int* __restrict__ tiles, int* __restrict__ ntiles) {
    __shared__ int hist[64];
    int tid = threadIdx.x;
    if (tid < 64) hist[tid] = 0;
    __syncthreads();
    for (int i = tid; i < T_TOK; i += 1024) atomicAdd(&hist[keys[i]], 1);
    __syncthreads();
    if (tid < 64) {  // one wave: shfl scan
        int n = hist[tid];
        int x = n;
#pragma unroll
        for (int d = 1; d < 64; d <<= 1) {
            int v = __shfl_up(x, d, 64);
            if (tid >= d) x += v;
        }
        int off = x - n;
        offs[tid] = off;
        cursor[tid] = 0;
        int tk = (n + 127) >> 7;
        int y = tk;
#pragma unroll
        for (int d = 1; d < 64; d <<= 1) {
            int v = __shfl_up(y, d, 64);
            if (tid >= d) y += v;
        }
        int tb = y - tk;
        for (int s = 0; s < tk; ++s) {
            tiles[4 * (tb + s) + 0] = tid;
            tiles[4 * (tb + s) + 1] = off + s * 128;
            int rem = n - s * 128;
            tiles[4 * (tb + s) + 2] = rem < 128 ? rem : 128;
        }
        if (tid == 63) *ntiles = y;
    }
}

__global__ void k_scatter(const int* __restrict__ keys, const int* __restrict__ offs,
                          int* __restrict__ cursor, int* __restrict__ perm) {
    int t = blockIdx.x * 256 + threadIdx.x;
    if (t < T_TOK) {
        int key = keys[t];
        int pos = offs[key] + atomicAdd(&cursor[key], 1);
        perm[pos] = t;
    }
}

// GEMM: block = 128 rows x 512 cols (4 col-iters of 128).
// A staged ONCE into 64KB swizzled LDS (gather+scale+cvt fused, rule-21
// both-sides swizzle: write side applies chunk^(row&7), read side same).
// B frags read register-direct from L2-resident Wt (16B contiguous).
// One barrier per block; 2 blocks/CU for overlap.
__global__ __launch_bounds__(256, 2) void k_gemm(
    const float* __restrict__ emb, const float* __restrict__ probs,
    const short* __restrict__ Wt, const float* __restrict__ bias,
    const int* __restrict__ perm, const int* __restrict__ tiles,
    const int* __restrict__ ntiles, float* __restrict__ out) {
    int tile_id = blockIdx.y;
    if (tile_id >= *ntiles) return;
    int key   = tiles[4 * tile_id + 0];
    int row0  = tiles[4 * tile_id + 1];
    int nrows = tiles[4 * tile_id + 2];
    int h0 = key >> 3, h1 = key & 7;

    __shared__ short As[128 * 256];  // 64 KB exactly

    int tid = threadIdx.x, lane = tid & 63, wave = tid >> 6;

    // ---- stage A: thread = (row r, slot hf); 128 f32 -> scaled bf16, swizzled
    {
        int r = tid >> 1, hf = tid & 1;
        int t = (r < nrows) ? perm[row0 + r] : -1;
        float p = (t >= 0) ? probs[2 * t + hf] : 0.f;
        const f32x4* src =
            (const f32x4*)(emb + ((size_t)(2 * (t < 0 ? 0 : t) + hf)) * DHD);
#pragma unroll
        for (int c = 0; c < 16; ++c) {
            f32x4 f0 = src[2 * c], f1 = src[2 * c + 1];
            bf16x8 o;
            o[0] = f2b(p * f0.x); o[1] = f2b(p * f0.y);
            o[2] = f2b(p * f0.z); o[3] = f2b(p * f0.w);
            o[4] = f2b(p * f1.x); o[5] = f2b(p * f1.y);
            o[6] = f2b(p * f1.z); o[7] = f2b(p * f1.w);
            int clog = hf * 16 + c;
            *(bf16x8*)(As + r * 256 + ((clog ^ (r & 7)) * 8)) = o;
        }
    }

    int l15 = lane & 15, lq = lane >> 4;
    int wm = (wave >> 1) * 64, wn = (wave & 1) * 64;

    // hoisted per-output-row token/prob (independent of col-iter)
    int rt[4][4]; float rp0[4][4], rp1[4][4];
#pragma unroll
    for (int mi = 0; mi < 4; ++mi)
#pragma unroll
        for (int rr = 0; rr < 4; ++rr) {
            int il = wm + mi * 16 + lq * 4 + rr;
            int tt = (il < nrows) ? perm[row0 + il] : -1;
            rt[mi][rr] = tt;
            int ts = tt < 0 ? 0 : tt;
            rp0[mi][rr] = probs[2 * ts];
            rp1[mi][rr] = probs[2 * ts + 1];
        }

    __syncthreads();

    for (int cb = 0; cb < 4; ++cb) {
        int ncol = blockIdx.x * 512 + cb * 128;
        f32x4 acc[4][4];
#pragma unroll
        for (int i = 0; i < 4; ++i)
#pragma unroll
            for (int j = 0; j < 4; ++j) acc[i][j] = (f32x4){0.f, 0.f, 0.f, 0.f};

#pragma unroll
        for (int kk = 0; kk < 8; ++kk) {
            bf16x8 af[4], bfr[4];
#pragma unroll
            for (int mi = 0; mi < 4; ++mi) {
                int R = wm + mi * 16 + l15;
                af[mi] = *(const bf16x8*)(As + R * 256 + (((kk * 4 + lq) ^ (R & 7)) * 8));
            }
            int h = (kk < 4) ? h0 : h1;
            const short* wb = Wt + (size_t)h * DMD * DHD + (kk & 3) * 32 + lq * 8;
#pragma unroll
            for (int ni = 0; ni < 4; ++ni) {
                int n = ncol + wn + ni * 16 + l15;
                bfr[ni] = *(const bf16x8*)(wb + (size_t)n * DHD);
            }
#pragma unroll
            for (int mi = 0; mi < 4; ++mi)
#pragma unroll
                for (int ni = 0; ni < 4; ++ni)
                    acc[mi][ni] = __builtin_amdgcn_mfma_f32_16x16x32_bf16(
                        af[mi], bfr[ni], acc[mi][ni], 0, 0, 0);
        }

        // epilogue for this col-block: prob-weighted bias, scatter-store rows
#pragma unroll
        for (int ni = 0; ni < 4; ++ni) {
            int c = ncol + wn + ni * 16 + l15;
            float b0 = bias[h0 * DMD + c];
            float b1 = bias[h1 * DMD + c];
#pragma unroll
            for (int mi = 0; mi < 4; ++mi)
#pragma unroll
                for (int rr = 0; rr < 4; ++rr) {
                    int tt = rt[mi][rr];
                    if (tt >= 0)
                        out[(size_t)tt * DMD + c] =
                            acc[mi][ni][rr] + rp0[mi][rr] * b0 + rp1[mi][rr] * b1;
                }
        }
    }
}

extern "C" void kernel_launch(void* const* d_in, const int* in_sizes, int n_in,
                              void* d_out, int out_size, void* d_ws, size_t ws_size,
                              hipStream_t stream) {
    const float* emb      = (const float*)d_in[0];  // (B,S,A,DH) f32
    const int*   sel_idx  = (const int*)d_in[1];    // (B,S,A) i32
    const float* sel_prob = (const float*)d_in[2];  // (B,S,A) f32
    const float* W        = (const float*)d_in[3];  // (H,DH,DM) f32
    const float* bias     = (const float*)d_in[4];  // (H,DM) f32
    float* out = (float*)d_out;

    char* ws = (char*)d_ws;
    int* offs   = (int*)(ws + 0);
    int* cursor = (int*)(ws + 256);
    int* ntiles = (int*)(ws + 512);
    int* tiles  = (int*)(ws + 1024);
    int* keys   = (int*)(ws + 8192);
    int* perm   = (int*)(ws + 73728);
    short* Wt   = (short*)(ws + 262144);

    k_keys_wt<<<dim3(64 + 256), dim3(256), 0, stream>>>(sel_idx, W, keys, Wt);
    k_scan<<<dim3(1), dim3(1024), 0, stream>>>(keys, offs, cursor, tiles, ntiles);
    k_scatter<<<dim3(T_TOK / 256), dim3(256), 0, stream>>>(keys, offs, cursor, perm);
    k_gemm<<<dim3(4, MAXTILES), dim3(256), 0, stream>>>(
        emb, sel_prob, Wt, bias, perm, tiles, ntiles, out);
}

// Round 6
// 120.513 us; speedup vs baseline: 2.0203x; 2.0203x over previous
//
#include <hip/hip_runtime.h>
#include <hip/hip_bf16.h>

// Problem constants (B=4, S=4096, A=2, H=8, DH=128, DM=2048)
#define T_TOK 16384
#define NH 8
#define DHD 128
#define DMD 2048
#define KTOT 256       // A=2 slots * DH=128
#define MAXTILES 192   // worst case: 64 buckets + 16384/128

typedef __attribute__((ext_vector_type(8))) short bf16x8;
typedef __attribute__((ext_vector_type(4))) float f32x4;

__device__ inline short f2b(float x) {
    __hip_bfloat16 h = __float2bfloat16(x);
    return *reinterpret_cast<short*>(&h);
}

// async global -> LDS, 16B per lane (dest = wave-uniform base + lane*16)
__device__ inline void gll16(const void* g, void* l) {
    __builtin_amdgcn_global_load_lds(
        (const __attribute__((address_space(1))) void*)g,
        (__attribute__((address_space(3))) void*)l, 16, 0, 0);
}

// ---------------- ws layout (bytes) ----------------
// 0      : offs[64]
// 256    : cursor[64]  (zeroed by k_scan each call)
// 512    : ntiles
// 1024   : tiles[192][4] int
// 8192   : keys[16384]  (64 KB)
// 73728  : perm[16384]  (64 KB)
// 262144 : Wt  bf16 [8][2048][128]    (4 MB)
// 4456448: Apk bf16 [16384+128][256]  (8.45 MB; slack rows never written —
//          read only into masked output rows, poison is finite bf16)

// fused: blocks [0,64) compute keys; blocks [64,320) transpose W -> Wt bf16
__global__ __launch_bounds__(256) void k_prep1(
    const int* __restrict__ idx, const float* __restrict__ W,
    int* __restrict__ keys, short* __restrict__ Wt) {
    if (blockIdx.x < 64) {
        int t = blockIdx.x * 256 + threadIdx.x;
        keys[t] = idx[2 * t] * NH + idx[2 * t + 1];
    } else {
        __shared__ float Ws[DHD][65];
        int bx = blockIdx.x - 64;
        int h = bx >> 5, m0 = (bx & 31) * 64;
        int tid = threadIdx.x;
        for (int i = tid; i < DHD * 64; i += 256) {
            int d = i >> 6, m = i & 63;
            Ws[d][m] = W[((size_t)h * DHD + d) * DMD + m0 + m];
        }
        __syncthreads();
        for (int i = tid; i < 64 * 16; i += 256) {
            int m = i >> 4, d0 = (i & 15) * 8;
            bf16x8 o;
#pragma unroll
            for (int j = 0; j < 8; ++j) o[j] = f2b(Ws[d0 + j][m]);
            *(bf16x8*)(Wt + ((size_t)h * DMD + m0 + m) * DHD + d0) = o;
        }
    }
}

// single block: hist (LDS atomics) -> exclusive scan -> offs/cursor/tiles
__global__ __launch_bounds__(1024) void k_scan(
    const int* __restrict__ keys, int* __restrict__ offs, int* __restrict__ cursor,
    int* __restrict__ tiles, int* __restrict__ ntiles) {
    __shared__ int hist[64];
    int tid = threadIdx.x;
    if (tid < 64) hist[tid] = 0;
    __syncthreads();
    for (int i = tid; i < T_TOK; i += 1024) atomicAdd(&hist[keys[i]], 1);
    __syncthreads();
    if (tid < 64) {
        int n = hist[tid];
        int x = n;
#pragma unroll
        for (int d = 1; d < 64; d <<= 1) {
            int v = __shfl_up(x, d, 64);
            if (tid >= d) x += v;
        }
        int off = x - n;
        offs[tid] = off;
        cursor[tid] = 0;
        int tk = (n + 127) >> 7;
        int y = tk;
#pragma unroll
        for (int d = 1; d < 64; d <<= 1) {
            int v = __shfl_up(y, d, 64);
            if (tid >= d) y += v;
        }
        int tb = y - tk;
        for (int s = 0; s < tk; ++s) {
            tiles[4 * (tb + s) + 0] = tid;
            tiles[4 * (tb + s) + 1] = off + s * 128;
            int rem = n - s * 128;
            tiles[4 * (tb + s) + 2] = rem < 128 ? rem : 128;
        }
        if (tid == 63) *ntiles = y;
    }
}

// fused scatter + pack: thread owns token t; finds its bucket slot, writes
// perm AND the routed/prob-scaled bf16 A row (output values are independent
// of intra-bucket atomic order -> deterministic).
__global__ __launch_bounds__(256) void k_scatpack(
    const int* __restrict__ keys, const float* __restrict__ emb,
    const float* __restrict__ probs, const int* __restrict__ offs,
    int* __restrict__ cursor, int* __restrict__ perm, short* __restrict__ Apk) {
    int t = blockIdx.x * 256 + threadIdx.x;
    int key = keys[t];
    int pos = offs[key] + atomicAdd(&cursor[key], 1);
    perm[pos] = t;
    float p0 = probs[2 * t], p1 = probs[2 * t + 1];
    const f32x4* s = (const f32x4*)(emb + (size_t)(2 * t) * DHD);
    short* dst = Apk + (size_t)pos * KTOT;
#pragma unroll 4
    for (int j = 0; j < 32; ++j) {
        float p = (j < 16) ? p0 : p1;
        f32x4 f0 = s[2 * j], f1 = s[2 * j + 1];
        bf16x8 o;
        o[0] = f2b(p * f0.x); o[1] = f2b(p * f0.y);
        o[2] = f2b(p * f0.z); o[3] = f2b(p * f0.w);
        o[4] = f2b(p * f1.x); o[5] = f2b(p * f1.y);
        o[6] = f2b(p * f1.z); o[7] = f2b(p * f1.w);
        *(bf16x8*)(dst + j * 8) = o;
    }
}

// m97-style GEMM (R3 core): BM=BN=128, BK=64, K=256 (4 steps), 32KB LDS ->
// 4 blocks/CU; gll16 staging, rule-21 both-sides XOR swizzle; XCD-chunked
// block swizzle (T1); non-temporal output stores.
__global__ __launch_bounds__(256) void k_gemm(
    const short* __restrict__ Apk, const float* __restrict__ probs,
    const short* __restrict__ Wt, const float* __restrict__ bias,
    const int* __restrict__ perm, const int* __restrict__ tiles,
    const int* __restrict__ ntiles, float* __restrict__ out) {
    // nwg = 16*192 = 3072; 384 contiguous work items per XCD
    int lin  = blockIdx.y * 16 + blockIdx.x;
    int work = (lin & 7) * 384 + (lin >> 3);
    int tile_id = work >> 4;
    int ncol    = (work & 15) * 128;
    if (tile_id >= *ntiles) return;
    int key   = tiles[4 * tile_id + 0];
    int row0  = tiles[4 * tile_id + 1];
    int nrows = tiles[4 * tile_id + 2];
    int h0 = key >> 3, h1 = key & 7;

    __shared__ short As[128 * 64];  // [row][chunk^(row&7)], 8 chunks x 16B
    __shared__ short Bs[128 * 64];
    __shared__ int   s_tok[128];
    __shared__ float s_p0[128], s_p1[128];

    int tid = threadIdx.x;
    int lane = tid & 63, wave = tid >> 6;

    if (tid < 128) {
        int t = -1; float p0 = 0.f, p1 = 0.f;
        if (tid < nrows) {
            t = perm[row0 + tid];
            p0 = probs[2 * t];
            p1 = probs[2 * t + 1];
        }
        s_tok[tid] = t; s_p0[tid] = p0; s_p1[tid] = p1;
    }

    f32x4 acc[4][4];
#pragma unroll
    for (int i = 0; i < 4; ++i)
#pragma unroll
        for (int j = 0; j < 4; ++j) acc[i][j] = (f32x4){0.f, 0.f, 0.f, 0.f};

    int wm = (wave >> 1) * 64, wn = (wave & 1) * 64;
    int l15 = lane & 15, lq = lane >> 4;

    int srcr = tid >> 3;        // dest row within 32-row round
    int cs   = (tid & 7) ^ (srcr & 7);  // inverse-swizzled source chunk

    for (int ks = 0; ks < 4; ++ks) {
        int h     = (ks < 2) ? h0 : h1;
        int kg0   = ks * 64;            // K offset within Apk row
        int dbase = (ks & 1) * 64;      // d offset within Wt row
#pragma unroll
        for (int rd = 0; rd < 4; ++rd) {
            int r = rd * 32 + srcr;
            short* ldst_a = As + (rd * 256 + wave * 64) * 8;  // wave-uniform
            short* ldst_b = Bs + (rd * 256 + wave * 64) * 8;
            gll16(Apk + (size_t)(row0 + r) * KTOT + kg0 + cs * 8, ldst_a);
            gll16(Wt + ((size_t)h * DMD + ncol + r) * DHD + dbase + cs * 8, ldst_b);
        }
        __syncthreads();

#pragma unroll
        for (int ki = 0; ki < 2; ++ki) {
            bf16x8 af[4], bfr[4];
#pragma unroll
            for (int mi = 0; mi < 4; ++mi) {
                int R  = wm + mi * 16 + l15;
                int ch = (ki * 4 + lq) ^ (R & 7);
                af[mi] = *(const bf16x8*)&As[R * 64 + ch * 8];
            }
#pragma unroll
            for (int ni = 0; ni < 4; ++ni) {
                int N  = wn + ni * 16 + l15;
                int ch = (ki * 4 + lq) ^ (N & 7);
                bfr[ni] = *(const bf16x8*)&Bs[N * 64 + ch * 8];
            }
#pragma unroll
            for (int mi = 0; mi < 4; ++mi)
#pragma unroll
                for (int ni = 0; ni < 4; ++ni)
                    acc[mi][ni] = __builtin_amdgcn_mfma_f32_16x16x32_bf16(
                        af[mi], bfr[ni], acc[mi][ni], 0, 0, 0);
        }
        __syncthreads();
    }

    // epilogue: prob-weighted bias, scatter rows to out (streaming -> NT)
#pragma unroll
    for (int ni = 0; ni < 4; ++ni) {
        int c = ncol + wn + ni * 16 + l15;
        float b0 = bias[h0 * DMD + c];
        float b1 = bias[h1 * DMD + c];
#pragma unroll
        for (int mi = 0; mi < 4; ++mi) {
#pragma unroll
            for (int r = 0; r < 4; ++r) {
                int i = wm + mi * 16 + lq * 4 + r;
                int t = s_tok[i];
                if (t >= 0) {
                    float v = acc[mi][ni][r] + s_p0[i] * b0 + s_p1[i] * b1;
                    __builtin_nontemporal_store(v, &out[(size_t)t * DMD + c]);
                }
            }
        }
    }
}

extern "C" void kernel_launch(void* const* d_in, const int* in_sizes, int n_in,
                              void* d_out, int out_size, void* d_ws, size_t ws_size,
                              hipStream_t stream) {
    const float* emb      = (const float*)d_in[0];  // (B,S,A,DH) f32
    const int*   sel_idx  = (const int*)d_in[1];    // (B,S,A) i32
    const float* sel_prob = (const float*)d_in[2];  // (B,S,A) f32
    const float* W        = (const float*)d_in[3];  // (H,DH,DM) f32
    const float* bias     = (const float*)d_in[4];  // (H,DM) f32
    float* out = (float*)d_out;

    char* ws = (char*)d_ws;
    int* offs   = (int*)(ws + 0);
    int* cursor = (int*)(ws + 256);
    int* ntiles = (int*)(ws + 512);
    int* tiles  = (int*)(ws + 1024);
    int* keys   = (int*)(ws + 8192);
    int* perm   = (int*)(ws + 73728);
    short* Wt   = (short*)(ws + 262144);
    short* Apk  = (short*)(ws + 4456448);

    k_prep1<<<dim3(320), dim3(256), 0, stream>>>(sel_idx, W, keys, Wt);
    k_scan<<<dim3(1), dim3(1024), 0, stream>>>(keys, offs, cursor, tiles, ntiles);
    k_scatpack<<<dim3(64), dim3(256), 0, stream>>>(
        keys, emb, sel_prob, offs, cursor, perm, Apk);
    k_gemm<<<dim3(16, MAXTILES), dim3(256), 0, stream>>>(
        Apk, sel_prob, Wt, bias, perm, tiles, ntiles, out);
}

// Round 8
// 119.925 us; speedup vs baseline: 2.0302x; 1.0049x over previous
//
#include <hip/hip_runtime.h>
#include <hip/hip_bf16.h>

// Problem constants (B=4, S=4096, A=2, H=8, DH=128, DM=2048)
#define T_TOK 16384
#define NH 8
#define DHD 128
#define DMD 2048
#define KTOT 256       // A=2 slots * DH=128
#define MAXTILES 192   // worst case: 64 buckets + 16384/128

typedef __attribute__((ext_vector_type(8))) short bf16x8;
typedef __attribute__((ext_vector_type(4))) float f32x4;

__device__ inline short f2b(float x) {
    __hip_bfloat16 h = __float2bfloat16(x);
    return *reinterpret_cast<short*>(&h);
}

// async global -> LDS, 16B per lane (dest = wave-uniform base + lane*16)
__device__ inline void gll16(const void* g, void* l) {
    __builtin_amdgcn_global_load_lds(
        (const __attribute__((address_space(1))) void*)g,
        (__attribute__((address_space(3))) void*)l, 16, 0, 0);
}

// ---------------- ws layout (bytes) ----------------
// 0      : offs[64]
// 256    : cursor[64]  (zeroed by k_scan each call)
// 512    : ntiles
// 1024   : tiles[192][4] int
// 8192   : keys[16384]  (64 KB)
// 73728  : perm[16384]  (64 KB)
// 262144 : Wt  bf16 [8][2048][128]    (4 MB)
// 4456448: Apk bf16 [16384+128][256]  (8.45 MB; slack rows never written —
//          read only into masked output rows, poison is finite bf16)

// fused: blocks [0,64) compute keys; blocks [64,320) transpose W -> Wt bf16
__global__ __launch_bounds__(256) void k_prep1(
    const int* __restrict__ idx, const float* __restrict__ W,
    int* __restrict__ keys, short* __restrict__ Wt) {
    if (blockIdx.x < 64) {
        int t = blockIdx.x * 256 + threadIdx.x;
        keys[t] = idx[2 * t] * NH + idx[2 * t + 1];
    } else {
        __shared__ float Ws[DHD][65];
        int bx = blockIdx.x - 64;
        int h = bx >> 5, m0 = (bx & 31) * 64;
        int tid = threadIdx.x;
        for (int i = tid; i < DHD * 64; i += 256) {
            int d = i >> 6, m = i & 63;
            Ws[d][m] = W[((size_t)h * DHD + d) * DMD + m0 + m];
        }
        __syncthreads();
        for (int i = tid; i < 64 * 16; i += 256) {
            int m = i >> 4, d0 = (i & 15) * 8;
            bf16x8 o;
#pragma unroll
            for (int j = 0; j < 8; ++j) o[j] = f2b(Ws[d0 + j][m]);
            *(bf16x8*)(Wt + ((size_t)h * DMD + m0 + m) * DHD + d0) = o;
        }
    }
}

// single block: hist (LDS atomics) -> exclusive scan -> offs/cursor/tiles
__global__ __launch_bounds__(1024) void k_scan(
    const int* __restrict__ keys, int* __restrict__ offs, int* __restrict__ cursor,
    int* __restrict__ tiles, int* __restrict__ ntiles) {
    __shared__ int hist[64];
    int tid = threadIdx.x;
    if (tid < 64) hist[tid] = 0;
    __syncthreads();
    for (int i = tid; i < T_TOK; i += 1024) atomicAdd(&hist[keys[i]], 1);
    __syncthreads();
    if (tid < 64) {
        int n = hist[tid];
        int x = n;
#pragma unroll
        for (int d = 1; d < 64; d <<= 1) {
            int v = __shfl_up(x, d, 64);
            if (tid >= d) x += v;
        }
        int off = x - n;
        offs[tid] = off;
        cursor[tid] = 0;
        int tk = (n + 127) >> 7;
        int y = tk;
#pragma unroll
        for (int d = 1; d < 64; d <<= 1) {
            int v = __shfl_up(y, d, 64);
            if (tid >= d) y += v;
        }
        int tb = y - tk;
        for (int s = 0; s < tk; ++s) {
            tiles[4 * (tb + s) + 0] = tid;
            tiles[4 * (tb + s) + 1] = off + s * 128;
            int rem = n - s * 128;
            tiles[4 * (tb + s) + 2] = rem < 128 ? rem : 128;
        }
        if (tid == 63) *ntiles = y;
    }
}

// fused scatter + pack, 8 threads per token: leader does the bucket atomic
// and perm write; pos broadcast via shfl; each thread packs 32 bf16 (64B).
// Output values are independent of intra-bucket atomic order -> deterministic.
__global__ __launch_bounds__(256) void k_scatpack(
    const int* __restrict__ keys, const float* __restrict__ emb,
    const float* __restrict__ probs, const int* __restrict__ offs,
    int* __restrict__ cursor, int* __restrict__ perm, short* __restrict__ Apk) {
    int g = blockIdx.x * 256 + threadIdx.x;   // 131072 threads = 16384 x 8
    int t = g >> 3, sub = g & 7;
    int lane = threadIdx.x & 63;
    int pos = 0;
    if (sub == 0) {
        int key = keys[t];
        pos = offs[key] + atomicAdd(&cursor[key], 1);
        perm[pos] = t;
    }
    pos = __shfl(pos, lane & ~7, 64);          // broadcast from group leader
    int a = sub >> 2;                          // slot 0 or 1
    float p = probs[2 * t + a];
    const f32x4* s =
        (const f32x4*)(emb + ((size_t)(2 * t + a)) * DHD + (sub & 3) * 32);
    short* dst = Apk + (size_t)pos * KTOT + sub * 32;
#pragma unroll
    for (int c = 0; c < 4; ++c) {
        f32x4 f0 = s[2 * c], f1 = s[2 * c + 1];
        bf16x8 o;
        o[0] = f2b(p * f0.x); o[1] = f2b(p * f0.y);
        o[2] = f2b(p * f0.z); o[3] = f2b(p * f0.w);
        o[4] = f2b(p * f1.x); o[5] = f2b(p * f1.y);
        o[6] = f2b(p * f1.z); o[7] = f2b(p * f1.w);
        *(bf16x8*)(dst + c * 8) = o;
    }
}

// m97-style GEMM: BM=BN=128, BK=64, K=256 (4 steps), 32KB LDS ->
// 4 blocks/CU (pinned via launch_bounds); gll16 staging, rule-21 both-sides
// XOR swizzle; XCD-chunked block swizzle (T1); non-temporal output stores.
__global__ __launch_bounds__(256, 4) void k_gemm(
    const short* __restrict__ Apk, const float* __restrict__ probs,
    const short* __restrict__ Wt, const float* __restrict__ bias,
    const int* __restrict__ perm, const int* __restrict__ tiles,
    const int* __restrict__ ntiles, float* __restrict__ out) {
    // nwg = 16*192 = 3072; 384 contiguous work items per XCD
    int lin  = blockIdx.y * 16 + blockIdx.x;
    int work = (lin & 7) * 384 + (lin >> 3);
    int tile_id = work >> 4;
    int ncol    = (work & 15) * 128;
    if (tile_id >= *ntiles) return;
    int key   = tiles[4 * tile_id + 0];
    int row0  = tiles[4 * tile_id + 1];
    int nrows = tiles[4 * tile_id + 2];
    int h0 = key >> 3, h1 = key & 7;

    __shared__ short As[128 * 64];  // [row][chunk^(row&7)], 8 chunks x 16B
    __shared__ short Bs[128 * 64];
    __shared__ int   s_tok[128];
    __shared__ float s_p0[128], s_p1[128];

    int tid = threadIdx.x;
    int lane = tid & 63, wave = tid >> 6;

    if (tid < 128) {
        int t = -1; float p0 = 0.f, p1 = 0.f;
        if (tid < nrows) {
            t = perm[row0 + tid];
            p0 = probs[2 * t];
            p1 = probs[2 * t + 1];
        }
        s_tok[tid] = t; s_p0[tid] = p0; s_p1[tid] = p1;
    }

    f32x4 acc[4][4];
#pragma unroll
    for (int i = 0; i < 4; ++i)
#pragma unroll
        for (int j = 0; j < 4; ++j) acc[i][j] = (f32x4){0.f, 0.f, 0.f, 0.f};

    int wm = (wave >> 1) * 64, wn = (wave & 1) * 64;
    int l15 = lane & 15, lq = lane >> 4;

    int srcr = tid >> 3;                // dest row within 32-row round
    int cs   = (tid & 7) ^ (srcr & 7);  // inverse-swizzled source chunk

    for (int ks = 0; ks < 4; ++ks) {
        int h     = (ks < 2) ? h0 : h1;
        int kg0   = ks * 64;            // K offset within Apk row
        int dbase = (ks & 1) * 64;      // d offset within Wt row
#pragma unroll
        for (int rd = 0; rd < 4; ++rd) {
            int r = rd * 32 + srcr;
            short* ldst_a = As + (rd * 256 + wave * 64) * 8;  // wave-uniform
            short* ldst_b = Bs + (rd * 256 + wave * 64) * 8;
            gll16(Apk + (size_t)(row0 + r) * KTOT + kg0 + cs * 8, ldst_a);
            gll16(Wt + ((size_t)h * DMD + ncol + r) * DHD + dbase + cs * 8, ldst_b);
        }
        __syncthreads();

#pragma unroll
        for (int ki = 0; ki < 2; ++ki) {
            bf16x8 af[4], bfr[4];
#pragma unroll
            for (int mi = 0; mi < 4; ++mi) {
                int R  = wm + mi * 16 + l15;
                int ch = (ki * 4 + lq) ^ (R & 7);
                af[mi] = *(const bf16x8*)&As[R * 64 + ch * 8];
            }
#pragma unroll
            for (int ni = 0; ni < 4; ++ni) {
                int N  = wn + ni * 16 + l15;
                int ch = (ki * 4 + lq) ^ (N & 7);
                bfr[ni] = *(const bf16x8*)&Bs[N * 64 + ch * 8];
            }
#pragma unroll
            for (int mi = 0; mi < 4; ++mi)
#pragma unroll
                for (int ni = 0; ni < 4; ++ni)
                    acc[mi][ni] = __builtin_amdgcn_mfma_f32_16x16x32_bf16(
                        af[mi], bfr[ni], acc[mi][ni], 0, 0, 0);
        }
        __syncthreads();
    }

    // epilogue: prob-weighted bias, scatter rows to out (streaming -> NT)
#pragma unroll
    for (int ni = 0; ni < 4; ++ni) {
        int c = ncol + wn + ni * 16 + l15;
        float b0 = bias[h0 * DMD + c];
        float b1 = bias[h1 * DMD + c];
#pragma unroll
        for (int mi = 0; mi < 4; ++mi) {
#pragma unroll
            for (int r = 0; r < 4; ++r) {
                int i = wm + mi * 16 + lq * 4 + r;
                int t = s_tok[i];
                if (t >= 0) {
                    float v = acc[mi][ni][r] + s_p0[i] * b0 + s_p1[i] * b1;
                    __builtin_nontemporal_store(v, &out[(size_t)t * DMD + c]);
                }
            }
        }
    }
}

extern "C" void kernel_launch(void* const* d_in, const int* in_sizes, int n_in,
                              void* d_out, int out_size, void* d_ws, size_t ws_size,
                              hipStream_t stream) {
    const float* emb      = (const float*)d_in[0];  // (B,S,A,DH) f32
    const int*   sel_idx  = (const int*)d_in[1];    // (B,S,A) i32
    const float* sel_prob = (const float*)d_in[2];  // (B,S,A) f32
    const float* W        = (const float*)d_in[3];  // (H,DH,DM) f32
    const float* bias     = (const float*)d_in[4];  // (H,DM) f32
    float* out = (float*)d_out;

    char* ws = (char*)d_ws;
    int* offs   = (int*)(ws + 0);
    int* cursor = (int*)(ws + 256);
    int* ntiles = (int*)(ws + 512);
    int* tiles  = (int*)(ws + 1024);
    int* keys   = (int*)(ws + 8192);
    int* perm   = (int*)(ws + 73728);
    short* Wt   = (short*)(ws + 262144);
    short* Apk  = (short*)(ws + 4456448);

    k_prep1<<<dim3(320), dim3(256), 0, stream>>>(sel_idx, W, keys, Wt);
    k_scan<<<dim3(1), dim3(1024), 0, stream>>>(keys, offs, cursor, tiles, ntiles);
    k_scatpack<<<dim3(512), dim3(256), 0, stream>>>(
        keys, emb, sel_prob, offs, cursor, perm, Apk);
    k_gemm<<<dim3(16, MAXTILES), dim3(256), 0, stream>>>(
        Apk, sel_prob, Wt, bias, perm, tiles, ntiles, out);
}